// Round 5
// baseline (844.434 us; speedup 1.0000x reference)
//
#include <hip/hip_runtime.h>

#define NB 32
#define NS 256
#define NT 512
#define KD3 256
#define KD2 768
#define NP 3072
#define KFZ 9216

__device__ __forceinline__ float wave_red_sum(float v) {
#pragma unroll
  for (int o = 32; o; o >>= 1) v += __shfl_xor(v, o, 64);
  return v;
}
__device__ __forceinline__ float wave_red_max(float v) {
#pragma unroll
  for (int o = 32; o; o >>= 1) v = fmaxf(v, __shfl_xor(v, o, 64));
  return v;
}

// ---------------- k1: f3p[b,p] -> c0[b][0:NP]; zero same range of c1..c3
__global__ __launch_bounds__(256) void k1_f3p(const float* __restrict__ f3d,
                                              const float* __restrict__ W3d,
                                              const float* __restrict__ b3d,
                                              float* __restrict__ c0, float* __restrict__ c1,
                                              float* __restrict__ c2, float* __restrict__ c3) {
  int b = blockIdx.x & 31, pc = blockIdx.x >> 5;  // 32 b x 12 pc
  __shared__ float4 xs[KD3 / 4];
  int tid = threadIdx.x;
  if (tid < KD3 / 4) xs[tid] = ((const float4*)(f3d + b * KD3))[tid];
  __syncthreads();
  int p = pc * 256 + tid;
  const float4* wrow = (const float4*)(W3d + (size_t)p * KD3);
  float acc = b3d[p];
#pragma unroll 8
  for (int i = 0; i < KD3 / 4; ++i) {
    float4 w = wrow[i], x = xs[i];
    acc = fmaf(w.x, x.x, acc); acc = fmaf(w.y, x.y, acc);
    acc = fmaf(w.z, x.z, acc); acc = fmaf(w.w, x.w, acc);
  }
  size_t o = (size_t)b * KFZ + p;
  c0[o] = acc; c1[o] = 0.f; c2[o] = 0.f; c3[o] = 0.f;
}

// ---------------- kT: online-softmax text pooling, explicit 2-row pipeline
// grid 512 = 32 b x 16 tch; wave handles 8 rows; partials Pt[c][b][p], ml[c][b]
__global__ __launch_bounds__(256, 2) void kT_text(const float* __restrict__ ftx,
                                                  const float* __restrict__ c0,
                                                  float* __restrict__ Pt,
                                                  float* __restrict__ ml) {
  int b = blockIdx.x & 31, tch = blockIdx.x >> 5;
  __shared__ float4 f4[NP / 4];
  int tid = threadIdx.x;
#pragma unroll
  for (int i = 0; i < 3; ++i)
    f4[tid + 256 * i] = ((const float4*)(c0 + (size_t)b * KFZ))[tid + 256 * i];
  __syncthreads();
  int wave = tid >> 6, lane = tid & 63;
  int t0 = tch * 32 + wave * 8;
  const float4* rbase = (const float4*)(ftx + ((size_t)(b * NT + t0)) * NP);
  float4 xa[12], xb[12];
#pragma unroll
  for (int j = 0; j < 12; ++j) xa[j] = rbase[lane + 64 * j];
  float m = -3.0e38f, l = 0.f;
  float4 acc[12];
#pragma unroll
  for (int j = 0; j < 12; ++j) acc[j] = make_float4(0.f, 0.f, 0.f, 0.f);
#pragma unroll
  for (int r = 0; r < 8; ++r) {
    float4* cur = (r & 1) ? xb : xa;
    float4* nxt = (r & 1) ? xa : xb;
    if (r < 7) {
      const float4* rn = rbase + (size_t)(r + 1) * (NP / 4);
#pragma unroll
      for (int j = 0; j < 12; ++j) nxt[j] = rn[lane + 64 * j];
    }
    float sx = 0.f, sy = 0.f, sz = 0.f, sw = 0.f;
#pragma unroll
    for (int j = 0; j < 12; ++j) {
      float4 f = f4[lane + 64 * j];
      sx = fmaf(cur[j].x, f.x, sx); sy = fmaf(cur[j].y, f.y, sy);
      sz = fmaf(cur[j].z, f.z, sz); sw = fmaf(cur[j].w, f.w, sw);
    }
    float s = (sx + sy) + (sz + sw);
    s = wave_red_sum(s);
    float mn = fmaxf(m, s);
    float al = __expf(m - mn);
    float e = __expf(s - mn);
    l = fmaf(l, al, e);
#pragma unroll
    for (int j = 0; j < 12; ++j) {
      acc[j].x = fmaf(acc[j].x, al, e * cur[j].x);
      acc[j].y = fmaf(acc[j].y, al, e * cur[j].y);
      acc[j].z = fmaf(acc[j].z, al, e * cur[j].z);
      acc[j].w = fmaf(acc[j].w, al, e * cur[j].w);
    }
    m = mn;
  }
  int c = tch * 4 + wave;
  float4* Pr = (float4*)(Pt + (size_t)(c * NB + b) * NP);
#pragma unroll
  for (int j = 0; j < 12; ++j) Pr[lane + 64 * j] = acc[j];
  if (lane == 0) { ml[(c * NB + b) * 2] = m; ml[(c * NB + b) * 2 + 1] = l; }
}

// ---------------- k2: g_part[kc][b][d] = sum_{p chunk} W2d[p,d]*f3p[b,p]; 96 blocks
__global__ __launch_bounds__(256) void k2_gpart(const float* __restrict__ W2d,
                                                const float* __restrict__ c0,
                                                float* __restrict__ g_part) {
  int dc = blockIdx.x % 3, kc = blockIdx.x / 3;
  __shared__ float xs[NB * 96];
  int tid = threadIdx.x;
  int p0 = kc * 96;
  for (int i = tid; i < NB * 96; i += 256) {
    int bb = i / 96, pp = i - bb * 96;
    xs[i] = c0[(size_t)bb * KFZ + p0 + pp];
  }
  __syncthreads();
  int d = dc * 256 + tid;
  float acc[NB];
#pragma unroll
  for (int b = 0; b < NB; ++b) acc[b] = 0.f;
  for (int pp = 0; pp < 96; pp += 8) {
    float w[8];
#pragma unroll
    for (int u = 0; u < 8; ++u) w[u] = W2d[(size_t)(p0 + pp + u) * KD2 + d];
#pragma unroll
    for (int b = 0; b < NB; ++b) {
      float4 x0 = *(const float4*)&xs[b * 96 + pp];
      float4 x1 = *(const float4*)&xs[b * 96 + pp + 4];
      acc[b] = fmaf(w[0], x0.x, acc[b]); acc[b] = fmaf(w[1], x0.y, acc[b]);
      acc[b] = fmaf(w[2], x0.z, acc[b]); acc[b] = fmaf(w[3], x0.w, acc[b]);
      acc[b] = fmaf(w[4], x1.x, acc[b]); acc[b] = fmaf(w[5], x1.y, acc[b]);
      acc[b] = fmaf(w[6], x1.z, acc[b]); acc[b] = fmaf(w[7], x1.w, acc[b]);
    }
  }
#pragma unroll
  for (int b = 0; b < NB; ++b) g_part[(size_t)(kc * NB + b) * KD2 + d] = acc[b];
}

// ---------------- k3a: scores_s raw; grid 256 = 32 b x 8 sc; wave: 8 rows in 2 groups of 4
__global__ __launch_bounds__(256) void k3a_scores(const float* __restrict__ f2d,
                                                  const float* __restrict__ g_part,
                                                  float* __restrict__ sraw) {
  int b = blockIdx.x & 31, sc = blockIdx.x >> 5;
  __shared__ float4 g4[KD2 / 4];
  float* g = (float*)g4;
  int tid = threadIdx.x;
  for (int i = tid; i < KD2; i += 256) {
    float a = 0.f;
#pragma unroll 8
    for (int c = 0; c < 32; ++c) a += g_part[(size_t)(c * NB + b) * KD2 + i];
    g[i] = a;
  }
  __syncthreads();
  int wave = tid >> 6, lane = tid & 63;
#pragma unroll
  for (int grp = 0; grp < 2; ++grp) {
    int s0 = sc * 32 + wave * 8 + grp * 4;
    float4 x[4][3];
#pragma unroll
    for (int rr = 0; rr < 4; ++rr) {
      const float4* row = (const float4*)(f2d + ((size_t)b * NS + s0 + rr) * KD2);
#pragma unroll
      for (int j = 0; j < 3; ++j) x[rr][j] = row[lane + 64 * j];
    }
#pragma unroll
    for (int rr = 0; rr < 4; ++rr) {
      float acc = 0.f;
#pragma unroll
      for (int j = 0; j < 3; ++j) {
        float4 f = g4[lane + 64 * j];
        acc = fmaf(x[rr][j].x, f.x, acc); acc = fmaf(x[rr][j].y, f.y, acc);
        acc = fmaf(x[rr][j].z, f.z, acc); acc = fmaf(x[rr][j].w, f.w, acc);
      }
      acc = wave_red_sum(acc);
      if (lane == 0) sraw[b * NS + s0 + rr] = acc;
    }
  }
}

// ---------------- kComb: combine 64 text partials -> c0[b][2NP..3NP); zero c1..c3
// grid 96 = 32 b x 3 pc
__global__ __launch_bounds__(256) void kComb(const float* __restrict__ Pt,
                                             const float* __restrict__ ml,
                                             float* __restrict__ c0, float* __restrict__ c1,
                                             float* __restrict__ c2, float* __restrict__ c3) {
  int b = blockIdx.x & 31, pc = blockIdx.x >> 5;
  __shared__ float sm[128];
  int tid = threadIdx.x;
  if (tid < 64) {
    sm[tid] = ml[(tid * NB + b) * 2];
    sm[64 + tid] = ml[(tid * NB + b) * 2 + 1];
  }
  __syncthreads();
  float M = -3.0e38f;
#pragma unroll 8
  for (int c = 0; c < 64; ++c) M = fmaxf(M, sm[c]);
  float denom = 0.f;
#pragma unroll 8
  for (int c = 0; c < 64; ++c) denom += __expf(sm[c] - M) * sm[64 + c];
  float inv = 1.f / denom;
  int p4 = pc * 1024 + tid * 4;
  float4 a = make_float4(0.f, 0.f, 0.f, 0.f);
#pragma unroll 2
  for (int cg = 0; cg < 8; ++cg) {
    float4 v[8];
#pragma unroll
    for (int u = 0; u < 8; ++u)
      v[u] = *(const float4*)&Pt[(size_t)((cg * 8 + u) * NB + b) * NP + p4];
#pragma unroll
    for (int u = 0; u < 8; ++u) {
      float w = __expf(sm[cg * 8 + u] - M);
      a.x = fmaf(w, v[u].x, a.x); a.y = fmaf(w, v[u].y, a.y);
      a.z = fmaf(w, v[u].z, a.z); a.w = fmaf(w, v[u].w, a.w);
    }
  }
  a.x *= inv; a.y *= inv; a.z *= inv; a.w *= inv;
  size_t o = (size_t)b * KFZ + 2 * NP + p4;
  float4 z = make_float4(0.f, 0.f, 0.f, 0.f);
  *(float4*)&c0[o] = a;
  *(float4*)&c1[o] = z; *(float4*)&c2[o] = z; *(float4*)&c3[o] = z;
}

// ---------------- k3c: softmax_s + partial f2d pooling; grid 384 = 32 b x 3 dc x 4 sc
__global__ __launch_bounds__(256) void k3c_sm(const float* __restrict__ f2d,
                                              const float* __restrict__ sraw,
                                              float* __restrict__ p2f) {
  int b = blockIdx.x & 31;
  int r = blockIdx.x >> 5;
  int dc = r % 3, sc = r / 3;
  __shared__ float pr[NS];
  __shared__ float red[8];
  int tid = threadIdx.x;
  int wave = tid >> 6, lane = tid & 63;
  float v = sraw[b * NS + tid];
  float mx = wave_red_max(v);
  if (lane == 0) red[wave] = mx;
  __syncthreads();
  float M = fmaxf(fmaxf(red[0], red[1]), fmaxf(red[2], red[3]));
  float e = __expf(v - M);
  pr[tid] = e;
  float smv = wave_red_sum(e);
  if (lane == 0) red[4 + wave] = smv;
  __syncthreads();
  float inv = 1.f / (red[4] + red[5] + red[6] + red[7]);
  int d = dc * 256 + tid;
  float acc = 0.f;
  const float* base = f2d + ((size_t)b * NS + sc * 64) * KD2 + d;
#pragma unroll 2
  for (int sg = 0; sg < 8; ++sg) {
    float xv[8];
#pragma unroll
    for (int u = 0; u < 8; ++u) xv[u] = base[(size_t)(sg * 8 + u) * KD2];
#pragma unroll
    for (int u = 0; u < 8; ++u) acc = fmaf(pr[sc * 64 + sg * 8 + u], xv[u], acc);
  }
  p2f[(size_t)(sc * NB + b) * KD2 + d] = acc * inv;
}

// ---------------- k5: pooled_2d = (sum of 4 p2f partials) @ W2d^T + b2d, k-split 4
// grid 192 = 48 pb x 4 ks
__global__ __launch_bounds__(256) void k5_pool2d(const float* __restrict__ W2d,
                                                 const float* __restrict__ b2d,
                                                 const float* __restrict__ p2f,
                                                 float* __restrict__ c0, float* __restrict__ c1,
                                                 float* __restrict__ c2, float* __restrict__ c3) {
  int pb = blockIdx.x >> 2, ks = blockIdx.x & 3;
  __shared__ __align__(16) float wt[64 * 68];
  __shared__ __align__(16) float xt[32 * 68];
  int tid = threadIdx.x;
  int tp = tid & 31, tb = tid >> 5;
  float acc[2][4];
#pragma unroll
  for (int i = 0; i < 2; ++i)
#pragma unroll
    for (int j = 0; j < 4; ++j) acc[i][j] = 0.f;
  for (int dk = 0; dk < 3; ++dk) {
    int d0 = ks * 192 + dk * 64;
#pragma unroll
    for (int it = 0; it < 4; ++it) {
      int idx = tid + it * 256;
      int row = idx >> 4, c4 = (idx & 15) * 4;
      *(float4*)&wt[row * 68 + c4] =
          *(const float4*)&W2d[(size_t)(pb * 64 + row) * KD2 + d0 + c4];
    }
#pragma unroll
    for (int it = 0; it < 2; ++it) {
      int idx = tid + it * 256;
      int row = idx >> 4, c4 = (idx & 15) * 4;
      float4 a = *(const float4*)&p2f[(size_t)row * KD2 + d0 + c4];
      float4 q1 = *(const float4*)&p2f[(size_t)(NB + row) * KD2 + d0 + c4];
      float4 q2 = *(const float4*)&p2f[(size_t)(2 * NB + row) * KD2 + d0 + c4];
      float4 q3 = *(const float4*)&p2f[(size_t)(3 * NB + row) * KD2 + d0 + c4];
      a.x += q1.x + q2.x + q3.x; a.y += q1.y + q2.y + q3.y;
      a.z += q1.z + q2.z + q3.z; a.w += q1.w + q2.w + q3.w;
      *(float4*)&xt[row * 68 + c4] = a;
    }
    __syncthreads();
#pragma unroll 4
    for (int kk = 0; kk < 64; kk += 4) {
      float4 wv[2], xv[4];
#pragma unroll
      for (int i = 0; i < 2; ++i) wv[i] = *(const float4*)&wt[(tp + 32 * i) * 68 + kk];
#pragma unroll
      for (int j = 0; j < 4; ++j) xv[j] = *(const float4*)&xt[(tb + 8 * j) * 68 + kk];
#pragma unroll
      for (int i = 0; i < 2; ++i)
#pragma unroll
        for (int j = 0; j < 4; ++j) {
          acc[i][j] = fmaf(wv[i].x, xv[j].x, acc[i][j]);
          acc[i][j] = fmaf(wv[i].y, xv[j].y, acc[i][j]);
          acc[i][j] = fmaf(wv[i].z, xv[j].z, acc[i][j]);
          acc[i][j] = fmaf(wv[i].w, xv[j].w, acc[i][j]);
        }
    }
    __syncthreads();
  }
  float* dst = (ks == 0) ? c0 : (ks == 1) ? c1 : (ks == 2) ? c2 : c3;
#pragma unroll
  for (int i = 0; i < 2; ++i) {
    int p = pb * 64 + tp + 32 * i;
    float bias = (ks == 0) ? b2d[p] : 0.f;
#pragma unroll
    for (int j = 0; j < 4; ++j)
      dst[(size_t)(tb + 8 * j) * KFZ + NP + p] = acc[i][j] + bias;
  }
}

// ---------------- k_csum: c0 += c1 + c2 + c3 (full concat); grid 288
__global__ __launch_bounds__(256) void k_csum(float* __restrict__ c0,
                                              const float* __restrict__ c1,
                                              const float* __restrict__ c2,
                                              const float* __restrict__ c3) {
  int i = blockIdx.x * 256 + threadIdx.x;
  float4 a = ((float4*)c0)[i];
  float4 v1 = ((const float4*)c1)[i];
  float4 v2 = ((const float4*)c2)[i];
  float4 v3 = ((const float4*)c3)[i];
  a.x += v1.x + v2.x + v3.x; a.y += v1.y + v2.y + v3.y;
  a.z += v1.z + v2.z + v3.z; a.w += v1.w + v2.w + v3.w;
  ((float4*)c0)[i] = a;
}

// ---------------- k6 v5: fused partial GEMM; grid 512 = 8 pb (384 p) x 64 kc (144 k)
// v3 post-mortem: grid 256 / 96KB LDS = 1 wave/SIMD + 64-line-per-instr staging ->
// in-flight-line starvation, k6 ran ~77us vs 20us model. v5 restores the two properties
// the proven round-0 k6 had: (a) COALESCED staging - 4 lanes per Wf row, each instr
// touches 16 fully-consumed 64B lines; (b) occupancy 3 blocks/CU (53.3KB LDS, lb(256,3))
// = 12 waves/CU for latency hiding. Keeps v3's conflict-free compute-read layout:
// k-slab-major wt[kk][row], slab stride padded to 385 float4 (385%8==1 -> staging
// writes spread across bank-quads; reads lane-consecutive).
__global__ __launch_bounds__(256, 3) void k6_fused(const float* __restrict__ Wf,
                                                   const float* __restrict__ c0,
                                                   float* __restrict__ fpart) {
  int pb = blockIdx.x & 7, kc = blockIdx.x >> 3;
  __shared__ float4 wt[2][4 * 385];  // 49.3 KB: [buf][kk4*385 + row], row<384
  __shared__ float4 xt[2][128];      // 4 KB:   [buf][kk4*32 + b]
  int tid = threadIdx.x;
  int wave = tid >> 6, lane = tid & 63;
  int p0g = pb * 384;
  int k00 = kc * 144;  // 9 tiles of 16 k

  float acc[6][8];
#pragma unroll
  for (int i = 0; i < 6; ++i)
#pragma unroll
    for (int j = 0; j < 8; ++j) acc[i][j] = 0.f;

  float4 st[6];  // 6 staging passes, 1 float4 each
  float4 xst;
  int srow = tid >> 2, skk = tid & 3;   // staging: 4 lanes per row
  int xb = tid & 31, xk = tid >> 5;     // for tid<128: b, kk4 of the x element

  auto LOADS = [&](int t) {  // global -> regs; 16 full 64B lines per instruction
    int k0 = k00 + t * 16;
#pragma unroll
    for (int r = 0; r < 6; ++r)
      st[r] = *(const float4*)&Wf[(size_t)(p0g + r * 64 + srow) * KFZ + k0 + skk * 4];
    if (tid < 128)
      xst = *(const float4*)&c0[(size_t)xb * KFZ + k0 + xk * 4];
  };
  auto WRITES = [&](int buf) {  // regs -> LDS; quad = (skk + row)%8 spreads banks
#pragma unroll
    for (int r = 0; r < 6; ++r)
      wt[buf][skk * 385 + r * 64 + srow] = st[r];
    if (tid < 128) xt[buf][tid] = xst;
  };

  LOADS(0);
  WRITES(0);
  __syncthreads();
  for (int t = 0; t < 9; ++t) {
    int buf = t & 1;
    if (t < 8) LOADS(t + 1);  // HBM latency hides under compute + 12 waves/CU
#pragma unroll
    for (int s = 0; s < 4; ++s) {
      float4 xv[8];
#pragma unroll
      for (int j = 0; j < 8; ++j) xv[j] = xt[buf][s * 32 + wave * 8 + j];
#pragma unroll
      for (int i = 0; i < 6; ++i) {
        float4 wv = wt[buf][s * 385 + i * 64 + lane];
#pragma unroll
        for (int j = 0; j < 8; ++j) {
          acc[i][j] = fmaf(wv.x, xv[j].x, acc[i][j]);
          acc[i][j] = fmaf(wv.y, xv[j].y, acc[i][j]);
          acc[i][j] = fmaf(wv.z, xv[j].z, acc[i][j]);
          acc[i][j] = fmaf(wv.w, xv[j].w, acc[i][j]);
        }
      }
    }
    if (t < 8) {
      WRITES(buf ^ 1);   // safe: buf^1 last read at t-1, all waves past the t-1 barrier
      __syncthreads();
    }
  }
  // fpart[kc][b][p], b = wave*8+j, p = p0g + lane + 64*i; coalesced across lanes
  float* fb = fpart + (size_t)(kc * NB + wave * 8) * NP + p0g + lane;
#pragma unroll
  for (int j = 0; j < 8; ++j)
#pragma unroll
    for (int i = 0; i < 6; ++i)
      fb[(size_t)j * NP + i * 64] = acc[i][j];
}

// ---------------- k7a: reduce 64 fpart chunks -> 8; grid 256 = 32 b x 8 g (full BW)
__global__ __launch_bounds__(256) void k7a_red(const float* __restrict__ fpart,
                                               float* __restrict__ fpart2) {
  int b = blockIdx.x & 31, g = blockIdx.x >> 5;
  int tid = threadIdx.x;
#pragma unroll
  for (int i = 0; i < 3; ++i) {
    int p4 = i * 256 + tid;  // float4 index within NP/4=768
    float4 a = make_float4(0.f, 0.f, 0.f, 0.f);
#pragma unroll
    for (int c = 0; c < 8; ++c) {
      float4 v = ((const float4*)&fpart[(size_t)((g * 8 + c) * NB + b) * NP])[p4];
      a.x += v.x; a.y += v.y; a.z += v.z; a.w += v.w;
    }
    ((float4*)&fpart2[(size_t)(g * NB + b) * NP])[p4] = a;
  }
}

// ---------------- k7b: out = bf + sum of 8 fpart2 chunks, broadcast over s
// grid 768 = 32 b x 3 pc x 8 sc (proven round-0 structure)
__global__ __launch_bounds__(256) void k7_bcast(const float* __restrict__ fpart2,
                                                const float* __restrict__ bfv,
                                                float* __restrict__ out) {
  int b = blockIdx.x & 31;
  int r = blockIdx.x >> 5;
  int pc = r % 3, sc = r / 3;  // pc<3, sc<8
  int tid = threadIdx.x;
  int p4 = pc * 1024 + 4 * tid;
  float4 v = *(const float4*)&bfv[p4];
#pragma unroll
  for (int c = 0; c < 8; ++c) {
    float4 a = *(const float4*)&fpart2[(size_t)(c * NB + b) * NP + p4];
    v.x += a.x; v.y += a.y; v.z += a.z; v.w += a.w;
  }
  float* obase = out + (size_t)b * NS * NP + p4;
#pragma unroll 4
  for (int ss = 0; ss < 32; ++ss) {
    int s = sc * 32 + ss;
    *(float4*)(obase + (size_t)s * NP) = v;
  }
}

extern "C" void kernel_launch(void* const* d_in, const int* in_sizes, int n_in,
                              void* d_out, int out_size, void* d_ws, size_t ws_size,
                              hipStream_t stream) {
  const float* f3d = (const float*)d_in[0];
  const float* f2d = (const float*)d_in[1];
  const float* ftx = (const float*)d_in[2];
  const float* W3d = (const float*)d_in[3];
  const float* b3d = (const float*)d_in[4];
  const float* W2d = (const float*)d_in[5];
  const float* b2d = (const float*)d_in[6];
  const float* Wf  = (const float*)d_in[7];
  const float* bfv = (const float*)d_in[8];
  float* out = (float*)d_out;
  float* ws = (float*)d_ws;

  // ws layout (floats)
  float* c0     = ws;                  // 294912
  float* c1     = ws + 294912;
  float* c2     = ws + 589824;
  float* c3     = ws + 884736;
  float* g_part = ws + 1179648;        // 786432
  float* sraw   = ws + 1966080;        // 8192
  float* p2f    = ws + 1974272;        // 4*32*768 = 98304
  float* ml     = ws + 2072576;        // 4096
  float* Pt     = ws + 2076672;        // 64*32*3072 = 6291456
  float* fpart  = ws + 8368128;        // 64*32*3072 = 6291456 (end ~58.6 MB)
  float* fpart2 = ws + 2076672;        // 8*32*3072 = 786432, reuses Pt (dead after kComb)

  k1_f3p<<<384, 256, 0, stream>>>(f3d, W3d, b3d, c0, c1, c2, c3);
  kT_text<<<512, 256, 0, stream>>>(ftx, c0, Pt, ml);
  k2_gpart<<<96, 256, 0, stream>>>(W2d, c0, g_part);
  k3a_scores<<<256, 256, 0, stream>>>(f2d, g_part, sraw);
  kComb<<<96, 256, 0, stream>>>(Pt, ml, c0, c1, c2, c3);
  k3c_sm<<<384, 256, 0, stream>>>(f2d, sraw, p2f);
  k5_pool2d<<<192, 256, 0, stream>>>(W2d, b2d, p2f, c0, c1, c2, c3);
  k_csum<<<288, 256, 0, stream>>>(c0, c1, c2, c3);
  k6_fused<<<512, 256, 0, stream>>>(Wf, c0, fpart);
  k7a_red<<<256, 256, 0, stream>>>(fpart, fpart2);
  k7_bcast<<<768, 256, 0, stream>>>(fpart2, bfv, out);
}

// Round 9
// 546.399 us; speedup vs baseline: 1.5455x; 1.5455x over previous
//
#include <hip/hip_runtime.h>

#define NB 32
#define NS 256
#define NT 512
#define KD3 256
#define KD2 768
#define NP 3072
#define KFZ 9216

__device__ __forceinline__ float wave_red_sum(float v) {
#pragma unroll
  for (int o = 32; o; o >>= 1) v += __shfl_xor(v, o, 64);
  return v;
}
__device__ __forceinline__ float wave_red_max(float v) {
#pragma unroll
  for (int o = 32; o; o >>= 1) v = fmaxf(v, __shfl_xor(v, o, 64));
  return v;
}

// ---------------- k1: f3p[b,p] -> c0[b][0:NP]; zero same range of c1..c3
__global__ __launch_bounds__(256) void k1_f3p(const float* __restrict__ f3d,
                                              const float* __restrict__ W3d,
                                              const float* __restrict__ b3d,
                                              float* __restrict__ c0, float* __restrict__ c1,
                                              float* __restrict__ c2, float* __restrict__ c3) {
  int b = blockIdx.x & 31, pc = blockIdx.x >> 5;  // 32 b x 12 pc
  __shared__ float4 xs[KD3 / 4];
  int tid = threadIdx.x;
  if (tid < KD3 / 4) xs[tid] = ((const float4*)(f3d + b * KD3))[tid];
  __syncthreads();
  int p = pc * 256 + tid;
  const float4* wrow = (const float4*)(W3d + (size_t)p * KD3);
  float acc = b3d[p];
#pragma unroll 8
  for (int i = 0; i < KD3 / 4; ++i) {
    float4 w = wrow[i], x = xs[i];
    acc = fmaf(w.x, x.x, acc); acc = fmaf(w.y, x.y, acc);
    acc = fmaf(w.z, x.z, acc); acc = fmaf(w.w, x.w, acc);
  }
  size_t o = (size_t)b * KFZ + p;
  c0[o] = acc; c1[o] = 0.f; c2[o] = 0.f; c3[o] = 0.f;
}

// ---------------- kT: online-softmax text pooling, explicit 2-row pipeline
// grid 512 = 32 b x 16 tch; wave handles 8 rows; partials Pt[c][b][p], ml[c][b]
__global__ __launch_bounds__(256, 2) void kT_text(const float* __restrict__ ftx,
                                                  const float* __restrict__ c0,
                                                  float* __restrict__ Pt,
                                                  float* __restrict__ ml) {
  int b = blockIdx.x & 31, tch = blockIdx.x >> 5;
  __shared__ float4 f4[NP / 4];
  int tid = threadIdx.x;
#pragma unroll
  for (int i = 0; i < 3; ++i)
    f4[tid + 256 * i] = ((const float4*)(c0 + (size_t)b * KFZ))[tid + 256 * i];
  __syncthreads();
  int wave = tid >> 6, lane = tid & 63;
  int t0 = tch * 32 + wave * 8;
  const float4* rbase = (const float4*)(ftx + ((size_t)(b * NT + t0)) * NP);
  float4 xa[12], xb[12];
#pragma unroll
  for (int j = 0; j < 12; ++j) xa[j] = rbase[lane + 64 * j];
  float m = -3.0e38f, l = 0.f;
  float4 acc[12];
#pragma unroll
  for (int j = 0; j < 12; ++j) acc[j] = make_float4(0.f, 0.f, 0.f, 0.f);
#pragma unroll
  for (int r = 0; r < 8; ++r) {
    float4* cur = (r & 1) ? xb : xa;
    float4* nxt = (r & 1) ? xa : xb;
    if (r < 7) {
      const float4* rn = rbase + (size_t)(r + 1) * (NP / 4);
#pragma unroll
      for (int j = 0; j < 12; ++j) nxt[j] = rn[lane + 64 * j];
    }
    float sx = 0.f, sy = 0.f, sz = 0.f, sw = 0.f;
#pragma unroll
    for (int j = 0; j < 12; ++j) {
      float4 f = f4[lane + 64 * j];
      sx = fmaf(cur[j].x, f.x, sx); sy = fmaf(cur[j].y, f.y, sy);
      sz = fmaf(cur[j].z, f.z, sz); sw = fmaf(cur[j].w, f.w, sw);
    }
    float s = (sx + sy) + (sz + sw);
    s = wave_red_sum(s);
    float mn = fmaxf(m, s);
    float al = __expf(m - mn);
    float e = __expf(s - mn);
    l = fmaf(l, al, e);
#pragma unroll
    for (int j = 0; j < 12; ++j) {
      acc[j].x = fmaf(acc[j].x, al, e * cur[j].x);
      acc[j].y = fmaf(acc[j].y, al, e * cur[j].y);
      acc[j].z = fmaf(acc[j].z, al, e * cur[j].z);
      acc[j].w = fmaf(acc[j].w, al, e * cur[j].w);
    }
    m = mn;
  }
  int c = tch * 4 + wave;
  float4* Pr = (float4*)(Pt + (size_t)(c * NB + b) * NP);
#pragma unroll
  for (int j = 0; j < 12; ++j) Pr[lane + 64 * j] = acc[j];
  if (lane == 0) { ml[(c * NB + b) * 2] = m; ml[(c * NB + b) * 2 + 1] = l; }
}

// ---------------- k2: g_part[kc][b][d] = sum_{p chunk} W2d[p,d]*f3p[b,p]; 96 blocks
__global__ __launch_bounds__(256) void k2_gpart(const float* __restrict__ W2d,
                                                const float* __restrict__ c0,
                                                float* __restrict__ g_part) {
  int dc = blockIdx.x % 3, kc = blockIdx.x / 3;
  __shared__ float xs[NB * 96];
  int tid = threadIdx.x;
  int p0 = kc * 96;
  for (int i = tid; i < NB * 96; i += 256) {
    int bb = i / 96, pp = i - bb * 96;
    xs[i] = c0[(size_t)bb * KFZ + p0 + pp];
  }
  __syncthreads();
  int d = dc * 256 + tid;
  float acc[NB];
#pragma unroll
  for (int b = 0; b < NB; ++b) acc[b] = 0.f;
  for (int pp = 0; pp < 96; pp += 8) {
    float w[8];
#pragma unroll
    for (int u = 0; u < 8; ++u) w[u] = W2d[(size_t)(p0 + pp + u) * KD2 + d];
#pragma unroll
    for (int b = 0; b < NB; ++b) {
      float4 x0 = *(const float4*)&xs[b * 96 + pp];
      float4 x1 = *(const float4*)&xs[b * 96 + pp + 4];
      acc[b] = fmaf(w[0], x0.x, acc[b]); acc[b] = fmaf(w[1], x0.y, acc[b]);
      acc[b] = fmaf(w[2], x0.z, acc[b]); acc[b] = fmaf(w[3], x0.w, acc[b]);
      acc[b] = fmaf(w[4], x1.x, acc[b]); acc[b] = fmaf(w[5], x1.y, acc[b]);
      acc[b] = fmaf(w[6], x1.z, acc[b]); acc[b] = fmaf(w[7], x1.w, acc[b]);
    }
  }
#pragma unroll
  for (int b = 0; b < NB; ++b) g_part[(size_t)(kc * NB + b) * KD2 + d] = acc[b];
}

// ---------------- k3a: scores_s raw; grid 256 = 32 b x 8 sc; wave: 8 rows in 2 groups of 4
__global__ __launch_bounds__(256) void k3a_scores(const float* __restrict__ f2d,
                                                  const float* __restrict__ g_part,
                                                  float* __restrict__ sraw) {
  int b = blockIdx.x & 31, sc = blockIdx.x >> 5;
  __shared__ float4 g4[KD2 / 4];
  float* g = (float*)g4;
  int tid = threadIdx.x;
  for (int i = tid; i < KD2; i += 256) {
    float a = 0.f;
#pragma unroll 8
    for (int c = 0; c < 32; ++c) a += g_part[(size_t)(c * NB + b) * KD2 + i];
    g[i] = a;
  }
  __syncthreads();
  int wave = tid >> 6, lane = tid & 63;
#pragma unroll
  for (int grp = 0; grp < 2; ++grp) {
    int s0 = sc * 32 + wave * 8 + grp * 4;
    float4 x[4][3];
#pragma unroll
    for (int rr = 0; rr < 4; ++rr) {
      const float4* row = (const float4*)(f2d + ((size_t)b * NS + s0 + rr) * KD2);
#pragma unroll
      for (int j = 0; j < 3; ++j) x[rr][j] = row[lane + 64 * j];
    }
#pragma unroll
    for (int rr = 0; rr < 4; ++rr) {
      float acc = 0.f;
#pragma unroll
      for (int j = 0; j < 3; ++j) {
        float4 f = g4[lane + 64 * j];
        acc = fmaf(x[rr][j].x, f.x, acc); acc = fmaf(x[rr][j].y, f.y, acc);
        acc = fmaf(x[rr][j].z, f.z, acc); acc = fmaf(x[rr][j].w, f.w, acc);
      }
      acc = wave_red_sum(acc);
      if (lane == 0) sraw[b * NS + s0 + rr] = acc;
    }
  }
}

// ---------------- kComb: combine 64 text partials -> c0[b][2NP..3NP); zero c1..c3
// grid 96 = 32 b x 3 pc
__global__ __launch_bounds__(256) void kComb(const float* __restrict__ Pt,
                                             const float* __restrict__ ml,
                                             float* __restrict__ c0, float* __restrict__ c1,
                                             float* __restrict__ c2, float* __restrict__ c3) {
  int b = blockIdx.x & 31, pc = blockIdx.x >> 5;
  __shared__ float sm[128];
  int tid = threadIdx.x;
  if (tid < 64) {
    sm[tid] = ml[(tid * NB + b) * 2];
    sm[64 + tid] = ml[(tid * NB + b) * 2 + 1];
  }
  __syncthreads();
  float M = -3.0e38f;
#pragma unroll 8
  for (int c = 0; c < 64; ++c) M = fmaxf(M, sm[c]);
  float denom = 0.f;
#pragma unroll 8
  for (int c = 0; c < 64; ++c) denom += __expf(sm[c] - M) * sm[64 + c];
  float inv = 1.f / denom;
  int p4 = pc * 1024 + tid * 4;
  float4 a = make_float4(0.f, 0.f, 0.f, 0.f);
#pragma unroll 2
  for (int cg = 0; cg < 8; ++cg) {
    float4 v[8];
#pragma unroll
    for (int u = 0; u < 8; ++u)
      v[u] = *(const float4*)&Pt[(size_t)((cg * 8 + u) * NB + b) * NP + p4];
#pragma unroll
    for (int u = 0; u < 8; ++u) {
      float w = __expf(sm[cg * 8 + u] - M);
      a.x = fmaf(w, v[u].x, a.x); a.y = fmaf(w, v[u].y, a.y);
      a.z = fmaf(w, v[u].z, a.z); a.w = fmaf(w, v[u].w, a.w);
    }
  }
  a.x *= inv; a.y *= inv; a.z *= inv; a.w *= inv;
  size_t o = (size_t)b * KFZ + 2 * NP + p4;
  float4 z = make_float4(0.f, 0.f, 0.f, 0.f);
  *(float4*)&c0[o] = a;
  *(float4*)&c1[o] = z; *(float4*)&c2[o] = z; *(float4*)&c3[o] = z;
}

// ---------------- k3c: softmax_s + partial f2d pooling; grid 384 = 32 b x 3 dc x 4 sc
__global__ __launch_bounds__(256) void k3c_sm(const float* __restrict__ f2d,
                                              const float* __restrict__ sraw,
                                              float* __restrict__ p2f) {
  int b = blockIdx.x & 31;
  int r = blockIdx.x >> 5;
  int dc = r % 3, sc = r / 3;
  __shared__ float pr[NS];
  __shared__ float red[8];
  int tid = threadIdx.x;
  int wave = tid >> 6, lane = tid & 63;
  float v = sraw[b * NS + tid];
  float mx = wave_red_max(v);
  if (lane == 0) red[wave] = mx;
  __syncthreads();
  float M = fmaxf(fmaxf(red[0], red[1]), fmaxf(red[2], red[3]));
  float e = __expf(v - M);
  pr[tid] = e;
  float smv = wave_red_sum(e);
  if (lane == 0) red[4 + wave] = smv;
  __syncthreads();
  float inv = 1.f / (red[4] + red[5] + red[6] + red[7]);
  int d = dc * 256 + tid;
  float acc = 0.f;
  const float* base = f2d + ((size_t)b * NS + sc * 64) * KD2 + d;
#pragma unroll 2
  for (int sg = 0; sg < 8; ++sg) {
    float xv[8];
#pragma unroll
    for (int u = 0; u < 8; ++u) xv[u] = base[(size_t)(sg * 8 + u) * KD2];
#pragma unroll
    for (int u = 0; u < 8; ++u) acc = fmaf(pr[sc * 64 + sg * 8 + u], xv[u], acc);
  }
  p2f[(size_t)(sc * NB + b) * KD2 + d] = acc * inv;
}

// ---------------- k5: pooled_2d = (sum of 4 p2f partials) @ W2d^T + b2d, k-split 4
// grid 192 = 48 pb x 4 ks
__global__ __launch_bounds__(256) void k5_pool2d(const float* __restrict__ W2d,
                                                 const float* __restrict__ b2d,
                                                 const float* __restrict__ p2f,
                                                 float* __restrict__ c0, float* __restrict__ c1,
                                                 float* __restrict__ c2, float* __restrict__ c3) {
  int pb = blockIdx.x >> 2, ks = blockIdx.x & 3;
  __shared__ __align__(16) float wt[64 * 68];
  __shared__ __align__(16) float xt[32 * 68];
  int tid = threadIdx.x;
  int tp = tid & 31, tb = tid >> 5;
  float acc[2][4];
#pragma unroll
  for (int i = 0; i < 2; ++i)
#pragma unroll
    for (int j = 0; j < 4; ++j) acc[i][j] = 0.f;
  for (int dk = 0; dk < 3; ++dk) {
    int d0 = ks * 192 + dk * 64;
#pragma unroll
    for (int it = 0; it < 4; ++it) {
      int idx = tid + it * 256;
      int row = idx >> 4, c4 = (idx & 15) * 4;
      *(float4*)&wt[row * 68 + c4] =
          *(const float4*)&W2d[(size_t)(pb * 64 + row) * KD2 + d0 + c4];
    }
#pragma unroll
    for (int it = 0; it < 2; ++it) {
      int idx = tid + it * 256;
      int row = idx >> 4, c4 = (idx & 15) * 4;
      float4 a = *(const float4*)&p2f[(size_t)row * KD2 + d0 + c4];
      float4 q1 = *(const float4*)&p2f[(size_t)(NB + row) * KD2 + d0 + c4];
      float4 q2 = *(const float4*)&p2f[(size_t)(2 * NB + row) * KD2 + d0 + c4];
      float4 q3 = *(const float4*)&p2f[(size_t)(3 * NB + row) * KD2 + d0 + c4];
      a.x += q1.x + q2.x + q3.x; a.y += q1.y + q2.y + q3.y;
      a.z += q1.z + q2.z + q3.z; a.w += q1.w + q2.w + q3.w;
      *(float4*)&xt[row * 68 + c4] = a;
    }
    __syncthreads();
#pragma unroll 4
    for (int kk = 0; kk < 64; kk += 4) {
      float4 wv[2], xv[4];
#pragma unroll
      for (int i = 0; i < 2; ++i) wv[i] = *(const float4*)&wt[(tp + 32 * i) * 68 + kk];
#pragma unroll
      for (int j = 0; j < 4; ++j) xv[j] = *(const float4*)&xt[(tb + 8 * j) * 68 + kk];
#pragma unroll
      for (int i = 0; i < 2; ++i)
#pragma unroll
        for (int j = 0; j < 4; ++j) {
          acc[i][j] = fmaf(wv[i].x, xv[j].x, acc[i][j]);
          acc[i][j] = fmaf(wv[i].y, xv[j].y, acc[i][j]);
          acc[i][j] = fmaf(wv[i].z, xv[j].z, acc[i][j]);
          acc[i][j] = fmaf(wv[i].w, xv[j].w, acc[i][j]);
        }
    }
    __syncthreads();
  }
  float* dst = (ks == 0) ? c0 : (ks == 1) ? c1 : (ks == 2) ? c2 : c3;
#pragma unroll
  for (int i = 0; i < 2; ++i) {
    int p = pb * 64 + tp + 32 * i;
    float bias = (ks == 0) ? b2d[p] : 0.f;
#pragma unroll
    for (int j = 0; j < 4; ++j)
      dst[(size_t)(tb + 8 * j) * KFZ + NP + p] = acc[i][j] + bias;
  }
}

// ---------------- k_csum: c0 += c1 + c2 + c3 (full concat); grid 288
__global__ __launch_bounds__(256) void k_csum(float* __restrict__ c0,
                                              const float* __restrict__ c1,
                                              const float* __restrict__ c2,
                                              const float* __restrict__ c3) {
  int i = blockIdx.x * 256 + threadIdx.x;
  float4 a = ((float4*)c0)[i];
  float4 v1 = ((const float4*)c1)[i];
  float4 v2 = ((const float4*)c2)[i];
  float4 v3 = ((const float4*)c3)[i];
  a.x += v1.x + v2.x + v3.x; a.y += v1.y + v2.y + v3.y;
  a.z += v1.z + v2.z + v3.z; a.w += v1.w + v2.w + v3.w;
  ((float4*)c0)[i] = a;
}

// ---------------- k6 v6: fused partial GEMM; grid 512 = 8 pb (384 p) x 64 kc (144 k)
// v5 post-mortem (rocprof): WRITE_SIZE 842MB (fpart ideal 25MB) + FETCH 554MB + VGPR=84
// => acc/st arrays demoted to SCRATCH (lambdas captured staging arrays by reference ->
// address escape -> SROA failure). v6: NO lambdas, NO register-staged st[] held across
// compute — staging is a plain load->LDS-store copy (round-0 style, never spilled),
// named locals only. Keeps v5's verified-correct compute indexing, conflict-free
// padded k-slab layout (stride 385), coalesced 4-lanes-per-row staging, double buffer,
// one barrier per tile. HBM-bound target ~25us (147MB @ ~6TB/s).
#define K6_STAGE(BUF, T)                                                         \
  do {                                                                           \
    int k0_ = k00 + (T) * 16;                                                    \
    const float* wb_ = Wf + (size_t)(p0g + srow) * KFZ + k0_ + skk * 4;          \
    float4 s0_ = *(const float4*)(wb_ + (size_t)(0 * 64) * KFZ);                 \
    float4 s1_ = *(const float4*)(wb_ + (size_t)(1 * 64) * KFZ);                 \
    float4 s2_ = *(const float4*)(wb_ + (size_t)(2 * 64) * KFZ);                 \
    float4 s3_ = *(const float4*)(wb_ + (size_t)(3 * 64) * KFZ);                 \
    float4 s4_ = *(const float4*)(wb_ + (size_t)(4 * 64) * KFZ);                 \
    float4 s5_ = *(const float4*)(wb_ + (size_t)(5 * 64) * KFZ);                 \
    float4 x_ = make_float4(0.f, 0.f, 0.f, 0.f);                                 \
    if (tid < 128) x_ = *(const float4*)&c0[(size_t)xb * KFZ + k0_ + xk * 4];    \
    wt[BUF][skk * 385 + 0 * 64 + srow] = s0_;                                    \
    wt[BUF][skk * 385 + 1 * 64 + srow] = s1_;                                    \
    wt[BUF][skk * 385 + 2 * 64 + srow] = s2_;                                    \
    wt[BUF][skk * 385 + 3 * 64 + srow] = s3_;                                    \
    wt[BUF][skk * 385 + 4 * 64 + srow] = s4_;                                    \
    wt[BUF][skk * 385 + 5 * 64 + srow] = s5_;                                    \
    if (tid < 128) xt[BUF][tid] = x_;                                            \
  } while (0)

__global__ __launch_bounds__(256) void k6_fused(const float* __restrict__ Wf,
                                                const float* __restrict__ c0,
                                                float* __restrict__ fpart) {
  int pb = blockIdx.x & 7, kc = blockIdx.x >> 3;
  __shared__ float4 wt[2][4 * 385];  // 49.3 KB: [buf][kk4*385 + row], row<384
  __shared__ float4 xt[2][128];      // 4 KB:   [buf][kk4*32 + b]
  int tid = threadIdx.x;
  int wave = tid >> 6, lane = tid & 63;
  int p0g = pb * 384;
  int k00 = kc * 144;  // 9 tiles of 16 k
  int srow = tid >> 2, skk = tid & 3;  // staging: 4 lanes per row (64B coalesced)
  int xb = tid & 31, xk = tid >> 5;    // for tid<128: b, kk4 of the x element

  float acc[6][8];
#pragma unroll
  for (int i = 0; i < 6; ++i)
#pragma unroll
    for (int j = 0; j < 8; ++j) acc[i][j] = 0.f;

  K6_STAGE(0, 0);
  __syncthreads();
  for (int t = 0; t < 9; ++t) {
    int buf = t & 1;
    if (t < 8) K6_STAGE(buf ^ 1, t + 1);  // copy next tile into other buffer
#pragma unroll
    for (int s = 0; s < 4; ++s) {
      float4 xv[8];
#pragma unroll
      for (int j = 0; j < 8; ++j) xv[j] = xt[buf][s * 32 + wave * 8 + j];
#pragma unroll
      for (int i = 0; i < 6; ++i) {
        float4 wv = wt[buf][s * 385 + i * 64 + lane];
#pragma unroll
        for (int j = 0; j < 8; ++j) {
          acc[i][j] = fmaf(wv.x, xv[j].x, acc[i][j]);
          acc[i][j] = fmaf(wv.y, xv[j].y, acc[i][j]);
          acc[i][j] = fmaf(wv.z, xv[j].z, acc[i][j]);
          acc[i][j] = fmaf(wv.w, xv[j].w, acc[i][j]);
        }
      }
    }
    __syncthreads();  // next buffer staged + all waves done reading buf
  }
  // fpart[kc][b][p], b = wave*8+j, p = p0g + lane + 64*i; coalesced across lanes
  float* fb = fpart + (size_t)(kc * NB + wave * 8) * NP + p0g + lane;
#pragma unroll
  for (int j = 0; j < 8; ++j)
#pragma unroll
    for (int i = 0; i < 6; ++i)
      fb[(size_t)j * NP + i * 64] = acc[i][j];
}

// ---------------- k7a: reduce 64 fpart chunks -> 8; grid 256 = 32 b x 8 g (full BW)
__global__ __launch_bounds__(256) void k7a_red(const float* __restrict__ fpart,
                                               float* __restrict__ fpart2) {
  int b = blockIdx.x & 31, g = blockIdx.x >> 5;
  int tid = threadIdx.x;
#pragma unroll
  for (int i = 0; i < 3; ++i) {
    int p4 = i * 256 + tid;  // float4 index within NP/4=768
    float4 a = make_float4(0.f, 0.f, 0.f, 0.f);
#pragma unroll
    for (int c = 0; c < 8; ++c) {
      float4 v = ((const float4*)&fpart[(size_t)((g * 8 + c) * NB + b) * NP])[p4];
      a.x += v.x; a.y += v.y; a.z += v.z; a.w += v.w;
    }
    ((float4*)&fpart2[(size_t)(g * NB + b) * NP])[p4] = a;
  }
}

// ---------------- k7b: out = bf + sum of 8 fpart2 chunks, broadcast over s
// grid 768 = 32 b x 3 pc x 8 sc (proven round-0 structure)
__global__ __launch_bounds__(256) void k7_bcast(const float* __restrict__ fpart2,
                                                const float* __restrict__ bfv,
                                                float* __restrict__ out) {
  int b = blockIdx.x & 31;
  int r = blockIdx.x >> 5;
  int pc = r % 3, sc = r / 3;  // pc<3, sc<8
  int tid = threadIdx.x;
  int p4 = pc * 1024 + 4 * tid;
  float4 v = *(const float4*)&bfv[p4];
#pragma unroll
  for (int c = 0; c < 8; ++c) {
    float4 a = *(const float4*)&fpart2[(size_t)(c * NB + b) * NP + p4];
    v.x += a.x; v.y += a.y; v.z += a.z; v.w += a.w;
  }
  float* obase = out + (size_t)b * NS * NP + p4;
#pragma unroll 4
  for (int ss = 0; ss < 32; ++ss) {
    int s = sc * 32 + ss;
    *(float4*)(obase + (size_t)s * NP) = v;
  }
}

extern "C" void kernel_launch(void* const* d_in, const int* in_sizes, int n_in,
                              void* d_out, int out_size, void* d_ws, size_t ws_size,
                              hipStream_t stream) {
  const float* f3d = (const float*)d_in[0];
  const float* f2d = (const float*)d_in[1];
  const float* ftx = (const float*)d_in[2];
  const float* W3d = (const float*)d_in[3];
  const float* b3d = (const float*)d_in[4];
  const float* W2d = (const float*)d_in[5];
  const float* b2d = (const float*)d_in[6];
  const float* Wf  = (const float*)d_in[7];
  const float* bfv = (const float*)d_in[8];
  float* out = (float*)d_out;
  float* ws = (float*)d_ws;

  // ws layout (floats)
  float* c0     = ws;                  // 294912
  float* c1     = ws + 294912;
  float* c2     = ws + 589824;
  float* c3     = ws + 884736;
  float* g_part = ws + 1179648;        // 786432
  float* sraw   = ws + 1966080;        // 8192
  float* p2f    = ws + 1974272;        // 4*32*768 = 98304
  float* ml     = ws + 2072576;        // 4096
  float* Pt     = ws + 2076672;        // 64*32*3072 = 6291456
  float* fpart  = ws + 8368128;        // 64*32*3072 = 6291456 (end ~58.6 MB)
  float* fpart2 = ws + 2076672;        // 8*32*3072 = 786432, reuses Pt (dead after kComb)

  k1_f3p<<<384, 256, 0, stream>>>(f3d, W3d, b3d, c0, c1, c2, c3);
  kT_text<<<512, 256, 0, stream>>>(ftx, c0, Pt, ml);
  k2_gpart<<<96, 256, 0, stream>>>(W2d, c0, g_part);
  k3a_scores<<<256, 256, 0, stream>>>(f2d, g_part, sraw);
  kComb<<<96, 256, 0, stream>>>(Pt, ml, c0, c1, c2, c3);
  k3c_sm<<<384, 256, 0, stream>>>(f2d, sraw, p2f);
  k5_pool2d<<<192, 256, 0, stream>>>(W2d, b2d, p2f, c0, c1, c2, c3);
  k_csum<<<288, 256, 0, stream>>>(c0, c1, c2, c3);
  k6_fused<<<512, 256, 0, stream>>>(Wf, c0, fpart);
  k7a_red<<<256, 256, 0, stream>>>(fpart, fpart2);
  k7_bcast<<<768, 256, 0, stream>>>(fpart2, bfv, out);
}